// Round 1
// baseline (387.037 us; speedup 1.0000x reference)
//
#include <hip/hip_runtime.h>
#include <cstdint>

#define OWD 126
#define MTOT 15876   // 126*126

typedef short bf16x8 __attribute__((ext_vector_type(8)));
typedef float f32x4  __attribute__((ext_vector_type(4)));

__device__ __forceinline__ uint16_t f2bf(float f) {
    union { float f; uint32_t u; } v;
    v.f = f;
    uint32_t u = v.u;
    // round-to-nearest-even truncation to bf16
    return (uint16_t)((u + 0x7FFFu + ((u >> 16) & 1u)) >> 16);
}

__device__ __forceinline__ uint32_t pk2(float a, float b) {
    return (uint32_t)f2bf(a) | ((uint32_t)f2bf(b) << 16);
}

// ---------------------------------------------------------------------------
// Prep: kernel [16][9][128 c][128 n] fp32  ->  Bt [16][128 n][1152 k] bf16
// k = rs*128 + c. Loads coalesced over n; each fp32 read exactly once.
// ---------------------------------------------------------------------------
__global__ __launch_bounds__(256) void kprep(const float* __restrict__ Kin,
                                             uint16_t* __restrict__ Bt) {
    const int rs = blockIdx.x;   // 0..8
    const int b  = blockIdx.y;   // 0..15
    const int t  = threadIdx.x;  // 0..255
    const int n  = t & 127;
    const int og = t >> 7;       // 0..1 -> octet group

    const float* src = Kin + (((size_t)b * 9 + rs) << 14);          // [c][n]
    uint16_t*    dst = Bt + ((size_t)b * 128 + n) * 1152 + rs * 128;

#pragma unroll
    for (int o = 0; o < 8; ++o) {
        const int oct = og * 8 + o;          // 0..15 (c-octet)
        const float* s0 = src + (oct * 8) * 128 + n;
        uint4 p;
        p.x = pk2(s0[0 * 128], s0[1 * 128]);
        p.y = pk2(s0[2 * 128], s0[3 * 128]);
        p.z = pk2(s0[4 * 128], s0[5 * 128]);
        p.w = pk2(s0[6 * 128], s0[7 * 128]);
        *(uint4*)(dst + oct * 8) = p;
    }
}

// ---------------------------------------------------------------------------
// Main: implicit-GEMM conv. Per block: 128x128 C-tile of one batch.
// M = spatial (oh*126+ow), N = Cout, K = rs*128+c (BK=64, 18 chunks).
// LDS tiles [128 rows][64 k] bf16, 16B-chunk XOR swizzle (chunk ^= row&7).
// ---------------------------------------------------------------------------
__global__ __launch_bounds__(256) void conv_mfma(const float* __restrict__ X,
                                                 const uint16_t* __restrict__ Bt,
                                                 float* __restrict__ Out) {
    __shared__ __align__(16) uint16_t lA[128 * 64];
    __shared__ __align__(16) uint16_t lB[128 * 64];

    const int mtile = blockIdx.x;  // 0..124
    const int b     = blockIdx.y;  // 0..15
    const int tid   = threadIdx.x;
    const int lane  = tid & 63;
    const int wave  = tid >> 6;
    const int wm    = (wave & 1) << 6;   // wave M offset (0/64)
    const int wn    = (wave >> 1) << 6;  // wave N offset (0/64)
    const int l15   = lane & 15;
    const int quad  = lane >> 4;

    // staging role: 2 threads per LDS row; each stages 32 elems (4 x 16B)
    const int srow  = tid >> 1;
    const int shalf = tid & 1;

    int m = mtile * 128 + srow;
    if (m >= MTOT) m = MTOT - 1;   // clamp; stores are guarded below
    const int oh = m / OWD;
    const int ow = m - oh * OWD;
    const float*    Xb = X + (((size_t)b * 128 + oh) * 128 + ow) * 128;
    const uint16_t* Bb = Bt + ((size_t)b * 128 + srow) * 1152 + shalf * 32;

    f32x4 acc[4][4];
#pragma unroll
    for (int i = 0; i < 4; ++i)
#pragma unroll
        for (int j = 0; j < 4; ++j)
            acc[i][j] = (f32x4){0.f, 0.f, 0.f, 0.f};

    for (int chunk = 0; chunk < 18; ++chunk) {
        const int rs = chunk >> 1;
        const int c0 = (chunk & 1) << 6;
        const int r  = rs / 3;
        const int s  = rs - r * 3;

        __syncthreads();

        // ---- stage A: X fp32 -> bf16 LDS ----
        {
            const float4* src = (const float4*)(Xb + (r * 128 + s) * 128 + c0 + shalf * 32);
            float4 v[8];
#pragma unroll
            for (int i = 0; i < 8; ++i) v[i] = src[i];
#pragma unroll
            for (int i = 0; i < 4; ++i) {
                uint4 p;
                p.x = pk2(v[2 * i].x, v[2 * i].y);
                p.y = pk2(v[2 * i].z, v[2 * i].w);
                p.z = pk2(v[2 * i + 1].x, v[2 * i + 1].y);
                p.w = pk2(v[2 * i + 1].z, v[2 * i + 1].w);
                const int ci = (shalf * 4 + i) ^ (srow & 7);
                *(uint4*)&lA[srow * 64 + ci * 8] = p;
            }
        }
        // ---- stage B: Bt bf16 -> LDS ----
        {
            const uint4* bsrc = (const uint4*)(Bb + rs * 128 + c0);
#pragma unroll
            for (int i = 0; i < 4; ++i) {
                const uint4 p = bsrc[i];
                const int ci = (shalf * 4 + i) ^ (srow & 7);
                *(uint4*)&lB[srow * 64 + ci * 8] = p;
            }
        }

        __syncthreads();

        // ---- compute: 2 ksubs x 16 MFMA per wave ----
#pragma unroll
        for (int ksub = 0; ksub < 2; ++ksub) {
            bf16x8 af[4], bfr[4];
#pragma unroll
            for (int i = 0; i < 4; ++i) {
                const int row = wm + i * 16 + l15;
                const int ci  = (ksub * 4 + quad) ^ (row & 7);
                af[i] = *(const bf16x8*)&lA[row * 64 + ci * 8];
            }
#pragma unroll
            for (int j = 0; j < 4; ++j) {
                const int row = wn + j * 16 + l15;
                const int ci  = (ksub * 4 + quad) ^ (row & 7);
                bfr[j] = *(const bf16x8*)&lB[row * 64 + ci * 8];
            }
#pragma unroll
            for (int i = 0; i < 4; ++i)
#pragma unroll
                for (int j = 0; j < 4; ++j)
                    acc[i][j] = __builtin_amdgcn_mfma_f32_16x16x32_bf16(
                        af[i], bfr[j], acc[i][j], 0, 0, 0);
        }
    }

    // ---- epilogue: D row = quad*4+reg, col = lane&15 ----
#pragma unroll
    for (int i = 0; i < 4; ++i) {
#pragma unroll
        for (int rr = 0; rr < 4; ++rr) {
            const int mrow = mtile * 128 + wm + i * 16 + quad * 4 + rr;
            if (mrow < MTOT) {
                const int oh2 = mrow / OWD;
                const int ow2 = mrow - oh2 * OWD;
                float* op = Out + (((size_t)b * OWD + oh2) * OWD + ow2) * 128 + wn + l15;
#pragma unroll
                for (int j = 0; j < 4; ++j)
                    op[j * 16] = acc[i][j][rr];
            }
        }
    }
}

extern "C" void kernel_launch(void* const* d_in, const int* in_sizes, int n_in,
                              void* d_out, int out_size, void* d_ws, size_t ws_size,
                              hipStream_t stream) {
    const float* X   = (const float*)d_in[0];   // [16,128,128,128]
    const float* Kin = (const float*)d_in[1];   // [16,3,3,128,128]
    float*       Out = (float*)d_out;           // [16,126,126,128]
    uint16_t*    Bt  = (uint16_t*)d_ws;         // [16,128,1152] bf16 (4.7 MB)

    kprep<<<dim3(9, 16), 256, 0, stream>>>(Kin, Bt);
    conv_mfma<<<dim3(125, 16), 256, 0, stream>>>(X, Bt, Out);
}

// Round 2
// 344.984 us; speedup vs baseline: 1.1219x; 1.1219x over previous
//
#include <hip/hip_runtime.h>
#include <cstdint>

#define OWD 126
#define MTOT 15876   // 126*126

typedef short bf16x8 __attribute__((ext_vector_type(8)));
typedef float f32x4  __attribute__((ext_vector_type(4)));

#define BT_ELEMS  (16u * 128u * 1152u)                 // 2,359,296 bf16
#define XBF_ELEMS (16u * 128u * 128u * 128u)           // 33,554,432 bf16
#define WS_NEEDED ((size_t)(BT_ELEMS + XBF_ELEMS) * 2) // ~71.8 MB

__device__ __forceinline__ uint16_t f2bf(float f) {
    union { float f; uint32_t u; } v;
    v.f = f;
    uint32_t u = v.u;
    return (uint16_t)((u + 0x7FFFu + ((u >> 16) & 1u)) >> 16);
}

__device__ __forceinline__ uint32_t pk2(float a, float b) {
    return (uint32_t)f2bf(a) | ((uint32_t)f2bf(b) << 16);
}

__device__ __forceinline__ void gl_lds16(const uint16_t* g, uint16_t* l) {
    __builtin_amdgcn_global_load_lds(
        (const __attribute__((address_space(1))) uint32_t*)g,
        (__attribute__((address_space(3))) uint32_t*)l, 16, 0, 0);
}

// ---------------------------------------------------------------------------
// Prep 1: kernel [16][9][128 c][128 n] fp32 -> Bt [16][128 n][1152 k] bf16
// ---------------------------------------------------------------------------
__global__ __launch_bounds__(256) void kprep(const float* __restrict__ Kin,
                                             uint16_t* __restrict__ Bt) {
    const int rs = blockIdx.x;   // 0..8
    const int b  = blockIdx.y;   // 0..15
    const int t  = threadIdx.x;
    const int n  = t & 127;
    const int og = t >> 7;

    const float* src = Kin + (((size_t)b * 9 + rs) << 14);
    uint16_t*    dst = Bt + ((size_t)b * 128 + n) * 1152 + rs * 128;

#pragma unroll
    for (int o = 0; o < 8; ++o) {
        const int oct = og * 8 + o;
        const float* s0 = src + (oct * 8) * 128 + n;
        uint4 p;
        p.x = pk2(s0[0 * 128], s0[1 * 128]);
        p.y = pk2(s0[2 * 128], s0[3 * 128]);
        p.z = pk2(s0[4 * 128], s0[5 * 128]);
        p.w = pk2(s0[6 * 128], s0[7 * 128]);
        *(uint4*)(dst + oct * 8) = p;
    }
}

// ---------------------------------------------------------------------------
// Prep 2: X fp32 NHWC -> bf16 NHWC (same layout), 8 elems/thread
// ---------------------------------------------------------------------------
__global__ __launch_bounds__(256) void xprep(const float* __restrict__ X,
                                             uint16_t* __restrict__ Xbf) {
    const size_t i = ((size_t)blockIdx.x * 256 + threadIdx.x) * 8;
    const float4 a = *(const float4*)(X + i);
    const float4 b = *(const float4*)(X + i + 4);
    uint4 p;
    p.x = pk2(a.x, a.y);
    p.y = pk2(a.z, a.w);
    p.z = pk2(b.x, b.y);
    p.w = pk2(b.z, b.w);
    *(uint4*)(Xbf + i) = p;
}

// ---------------------------------------------------------------------------
// Main (fast path): implicit-GEMM conv, m97 structure.
// 128x128 C-tile per block, BK=32 (36 chunks), global_load_lds staging,
// linear [row][32k] bf16 LDS (64B rows -> bank-balanced ds_read_b128).
// ---------------------------------------------------------------------------
__global__ __launch_bounds__(256) void conv_mfma_a(const uint16_t* __restrict__ Xbf,
                                                   const uint16_t* __restrict__ Bt,
                                                   float* __restrict__ Out) {
    __shared__ __align__(16) uint16_t lA[128 * 32];
    __shared__ __align__(16) uint16_t lB[128 * 32];

    const int mtile = blockIdx.x;  // 0..124
    const int b     = blockIdx.y;  // 0..15
    const int tid   = threadIdx.x;
    const int lane  = tid & 63;
    const int wave  = tid >> 6;
    const int wm    = (wave & 1) << 6;
    const int wn    = (wave >> 1) << 6;
    const int l15   = lane & 15;
    const int quad  = lane >> 4;

    // staging role: 4 threads per LDS row, each one 16B chunk; two 64-row halves
    const int row = tid >> 2;      // 0..63
    const int kq  = tid & 3;       // 16B chunk within 64B row

    int m0 = mtile * 128 + row;        if (m0 >= MTOT) m0 = MTOT - 1;
    int m1 = mtile * 128 + 64 + row;   if (m1 >= MTOT) m1 = MTOT - 1;
    const int oh0 = m0 / OWD, ow0 = m0 - oh0 * OWD;
    const int oh1 = m1 / OWD, ow1 = m1 - oh1 * OWD;

    const uint16_t* Xr0 = Xbf + (((size_t)b * 128 + oh0) * 128 + ow0) * 128 + kq * 8;
    const uint16_t* Xr1 = Xbf + (((size_t)b * 128 + oh1) * 128 + ow1) * 128 + kq * 8;
    const uint16_t* Br0 = Bt + ((size_t)b * 128 + row) * 1152 + kq * 8;
    const uint16_t* Br1 = Bt + ((size_t)b * 128 + 64 + row) * 1152 + kq * 8;

    uint16_t* lA0 = &lA[tid * 8];
    uint16_t* lA1 = &lA[2048 + tid * 8];
    uint16_t* lB0 = &lB[tid * 8];
    uint16_t* lB1 = &lB[2048 + tid * 8];

    f32x4 acc[4][4];
#pragma unroll
    for (int i = 0; i < 4; ++i)
#pragma unroll
        for (int j = 0; j < 4; ++j)
            acc[i][j] = (f32x4){0.f, 0.f, 0.f, 0.f};

    for (int rs = 0; rs < 9; ++rs) {
        const int r = rs / 3;
        const int s = rs - r * 3;
        const int aoff0 = (r * 128 + s) * 128;
        const int boff0 = rs * 128;
#pragma unroll
        for (int cs = 0; cs < 4; ++cs) {
            const int c0 = cs * 32;

            __syncthreads();
            gl_lds16(Xr0 + aoff0 + c0, lA0);
            gl_lds16(Xr1 + aoff0 + c0, lA1);
            gl_lds16(Br0 + boff0 + c0, lB0);
            gl_lds16(Br1 + boff0 + c0, lB1);
            __syncthreads();

            bf16x8 af[4], bfr[4];
#pragma unroll
            for (int i = 0; i < 4; ++i)
                af[i] = *(const bf16x8*)&lA[(wm + i * 16 + l15) * 32 + quad * 8];
#pragma unroll
            for (int j = 0; j < 4; ++j)
                bfr[j] = *(const bf16x8*)&lB[(wn + j * 16 + l15) * 32 + quad * 8];
#pragma unroll
            for (int i = 0; i < 4; ++i)
#pragma unroll
                for (int j = 0; j < 4; ++j)
                    acc[i][j] = __builtin_amdgcn_mfma_f32_16x16x32_bf16(
                        af[i], bfr[j], acc[i][j], 0, 0, 0);
        }
    }

    // epilogue: D row = quad*4+reg, col = lane&15 (verified round 1)
#pragma unroll
    for (int i = 0; i < 4; ++i) {
#pragma unroll
        for (int rr = 0; rr < 4; ++rr) {
            const int mrow = mtile * 128 + wm + i * 16 + quad * 4 + rr;
            if (mrow < MTOT) {
                const int oh2 = mrow / OWD;
                const int ow2 = mrow - oh2 * OWD;
                float* op = Out + (((size_t)b * OWD + oh2) * OWD + ow2) * 128 + wn + l15;
#pragma unroll
                for (int j = 0; j < 4; ++j)
                    op[j * 16] = acc[i][j][rr];
            }
        }
    }
}

// ---------------------------------------------------------------------------
// Fallback (ws too small): round-1 kernel, fp32 X with in-kernel cvt.
// ---------------------------------------------------------------------------
__global__ __launch_bounds__(256) void conv_mfma(const float* __restrict__ X,
                                                 const uint16_t* __restrict__ Bt,
                                                 float* __restrict__ Out) {
    __shared__ __align__(16) uint16_t lA[128 * 64];
    __shared__ __align__(16) uint16_t lB[128 * 64];

    const int mtile = blockIdx.x;
    const int b     = blockIdx.y;
    const int tid   = threadIdx.x;
    const int lane  = tid & 63;
    const int wave  = tid >> 6;
    const int wm    = (wave & 1) << 6;
    const int wn    = (wave >> 1) << 6;
    const int l15   = lane & 15;
    const int quad  = lane >> 4;

    const int srow  = tid >> 1;
    const int shalf = tid & 1;

    int m = mtile * 128 + srow;
    if (m >= MTOT) m = MTOT - 1;
    const int oh = m / OWD;
    const int ow = m - oh * OWD;
    const float*    Xb = X + (((size_t)b * 128 + oh) * 128 + ow) * 128;
    const uint16_t* Bb = Bt + ((size_t)b * 128 + srow) * 1152 + shalf * 32;

    f32x4 acc[4][4];
#pragma unroll
    for (int i = 0; i < 4; ++i)
#pragma unroll
        for (int j = 0; j < 4; ++j)
            acc[i][j] = (f32x4){0.f, 0.f, 0.f, 0.f};

    for (int chunk = 0; chunk < 18; ++chunk) {
        const int rs = chunk >> 1;
        const int c0 = (chunk & 1) << 6;
        const int r  = rs / 3;
        const int s  = rs - r * 3;

        __syncthreads();
        {
            const float4* src = (const float4*)(Xb + (r * 128 + s) * 128 + c0 + shalf * 32);
            float4 v[8];
#pragma unroll
            for (int i = 0; i < 8; ++i) v[i] = src[i];
#pragma unroll
            for (int i = 0; i < 4; ++i) {
                uint4 p;
                p.x = pk2(v[2 * i].x, v[2 * i].y);
                p.y = pk2(v[2 * i].z, v[2 * i].w);
                p.z = pk2(v[2 * i + 1].x, v[2 * i + 1].y);
                p.w = pk2(v[2 * i + 1].z, v[2 * i + 1].w);
                const int ci = (shalf * 4 + i) ^ (srow & 7);
                *(uint4*)&lA[srow * 64 + ci * 8] = p;
            }
        }
        {
            const uint4* bsrc = (const uint4*)(Bb + rs * 128 + c0);
#pragma unroll
            for (int i = 0; i < 4; ++i) {
                const uint4 p = bsrc[i];
                const int ci = (shalf * 4 + i) ^ (srow & 7);
                *(uint4*)&lB[srow * 64 + ci * 8] = p;
            }
        }
        __syncthreads();

#pragma unroll
        for (int ksub = 0; ksub < 2; ++ksub) {
            bf16x8 af[4], bfr[4];
#pragma unroll
            for (int i = 0; i < 4; ++i) {
                const int row = wm + i * 16 + l15;
                const int ci  = (ksub * 4 + quad) ^ (row & 7);
                af[i] = *(const bf16x8*)&lA[row * 64 + ci * 8];
            }
#pragma unroll
            for (int j = 0; j < 4; ++j) {
                const int row = wn + j * 16 + l15;
                const int ci  = (ksub * 4 + quad) ^ (row & 7);
                bfr[j] = *(const bf16x8*)&lB[row * 64 + ci * 8];
            }
#pragma unroll
            for (int i = 0; i < 4; ++i)
#pragma unroll
                for (int j = 0; j < 4; ++j)
                    acc[i][j] = __builtin_amdgcn_mfma_f32_16x16x32_bf16(
                        af[i], bfr[j], acc[i][j], 0, 0, 0);
        }
    }

#pragma unroll
    for (int i = 0; i < 4; ++i) {
#pragma unroll
        for (int rr = 0; rr < 4; ++rr) {
            const int mrow = mtile * 128 + wm + i * 16 + quad * 4 + rr;
            if (mrow < MTOT) {
                const int oh2 = mrow / OWD;
                const int ow2 = mrow - oh2 * OWD;
                float* op = Out + (((size_t)b * OWD + oh2) * OWD + ow2) * 128 + wn + l15;
#pragma unroll
                for (int j = 0; j < 4; ++j)
                    op[j * 16] = acc[i][j][rr];
            }
        }
    }
}

extern "C" void kernel_launch(void* const* d_in, const int* in_sizes, int n_in,
                              void* d_out, int out_size, void* d_ws, size_t ws_size,
                              hipStream_t stream) {
    const float* X   = (const float*)d_in[0];   // [16,128,128,128]
    const float* Kin = (const float*)d_in[1];   // [16,3,3,128,128]
    float*       Out = (float*)d_out;           // [16,126,126,128]
    uint16_t*    Bt  = (uint16_t*)d_ws;         // bf16 [16][128][1152]
    uint16_t*    Xbf = Bt + BT_ELEMS;           // bf16 [16][128][128][128]

    kprep<<<dim3(9, 16), 256, 0, stream>>>(Kin, Bt);
    if (ws_size >= WS_NEEDED) {
        xprep<<<XBF_ELEMS / (256 * 8), 256, 0, stream>>>(X, Xbf);
        conv_mfma_a<<<dim3(125, 16), 256, 0, stream>>>(Xbf, Bt, Out);
    } else {
        conv_mfma<<<dim3(125, 16), 256, 0, stream>>>(X, Bt, Out);
    }
}

// Round 3
// 326.652 us; speedup vs baseline: 1.1849x; 1.0561x over previous
//
#include <hip/hip_runtime.h>
#include <cstdint>

#define OWD 126
#define MTOT 15876   // 126*126

typedef short bf16x8 __attribute__((ext_vector_type(8)));
typedef float f32x4  __attribute__((ext_vector_type(4)));

#define BT_ELEMS  (16u * 128u * 1152u)                 // 2,359,296 bf16
#define XBF_ELEMS (16u * 128u * 128u * 128u)           // 33,554,432 bf16
#define WS_NEEDED ((size_t)(BT_ELEMS + XBF_ELEMS) * 2) // ~71.8 MB

__device__ __forceinline__ uint16_t f2bf(float f) {
    union { float f; uint32_t u; } v;
    v.f = f;
    uint32_t u = v.u;
    return (uint16_t)((u + 0x7FFFu + ((u >> 16) & 1u)) >> 16);
}

__device__ __forceinline__ uint32_t pk2(float a, float b) {
    return (uint32_t)f2bf(a) | ((uint32_t)f2bf(b) << 16);
}

__device__ __forceinline__ void gl_lds16(const uint16_t* g, uint16_t* l) {
    __builtin_amdgcn_global_load_lds(
        (const __attribute__((address_space(1))) uint32_t*)g,
        (__attribute__((address_space(3))) uint32_t*)l, 16, 0, 0);
}

// ---------------------------------------------------------------------------
// Prep 1: kernel [16][9][128 c][128 n] fp32 -> Bt [16][128 n][1152 k] bf16
// ---------------------------------------------------------------------------
__global__ __launch_bounds__(256) void kprep(const float* __restrict__ Kin,
                                             uint16_t* __restrict__ Bt) {
    const int rs = blockIdx.x;   // 0..8
    const int b  = blockIdx.y;   // 0..15
    const int t  = threadIdx.x;
    const int n  = t & 127;
    const int og = t >> 7;

    const float* src = Kin + (((size_t)b * 9 + rs) << 14);
    uint16_t*    dst = Bt + ((size_t)b * 128 + n) * 1152 + rs * 128;

#pragma unroll
    for (int o = 0; o < 8; ++o) {
        const int oct = og * 8 + o;
        const float* s0 = src + (oct * 8) * 128 + n;
        uint4 p;
        p.x = pk2(s0[0 * 128], s0[1 * 128]);
        p.y = pk2(s0[2 * 128], s0[3 * 128]);
        p.z = pk2(s0[4 * 128], s0[5 * 128]);
        p.w = pk2(s0[6 * 128], s0[7 * 128]);
        *(uint4*)(dst + oct * 8) = p;
    }
}

// ---------------------------------------------------------------------------
// Prep 2: X fp32 NHWC -> bf16 NHWC (same layout), 8 elems/thread
// ---------------------------------------------------------------------------
__global__ __launch_bounds__(256) void xprep(const float* __restrict__ X,
                                             uint16_t* __restrict__ Xbf) {
    const size_t i = ((size_t)blockIdx.x * 256 + threadIdx.x) * 8;
    const float4 a = *(const float4*)(X + i);
    const float4 b = *(const float4*)(X + i + 4);
    uint4 p;
    p.x = pk2(a.x, a.y);
    p.y = pk2(a.z, a.w);
    p.z = pk2(b.x, b.y);
    p.w = pk2(b.z, b.w);
    *(uint4*)(Xbf + i) = p;
}

// ---------------------------------------------------------------------------
// Main: implicit-GEMM conv. 128x128 C-tile per block, BK=64 (18 chunks),
// global_load_lds staging with XOR-swizzled chunk->slot mapping:
//   LDS tile [128 rows][64 k] bf16, 128B rows; logical 16B chunk kc of row r
//   lives at physical slot kc^(r&7)  ->  ds_read_b128 conflict-free.
// Staging lane l fetches chunk kc=(l&7)^(l>>3) so its fixed LDS slot
// (wave base + lane*16) holds the right data; each row still one
// contiguous 128B global run (coalesced).
// ---------------------------------------------------------------------------
__global__ __launch_bounds__(256) void conv_mfma_a(const uint16_t* __restrict__ Xbf,
                                                   const uint16_t* __restrict__ Bt,
                                                   float* __restrict__ Out) {
    __shared__ __align__(16) uint16_t lA[128 * 64];
    __shared__ __align__(16) uint16_t lB[128 * 64];

    const int mtile = blockIdx.x;  // 0..124
    const int b     = blockIdx.y;  // 0..15
    const int tid   = threadIdx.x;
    const int lane  = tid & 63;
    const int wave  = tid >> 6;
    const int wm    = (wave & 1) << 6;
    const int wn    = (wave >> 1) << 6;
    const int l15   = lane & 15;
    const int quad  = lane >> 4;

    // staging: lane l, iter i covers LDS slot s = wave*256 + i*64 + lane
    //   row = s>>3 = wave*32 + i*8 + (lane>>3), pslot = lane&7
    //   logical chunk kc = pslot ^ (row&7) = (lane&7) ^ (lane>>3)
    const int kc = (lane & 7) ^ (lane >> 3);
    const uint16_t* Asrc[4];
    const uint16_t* Bsrc[4];
#pragma unroll
    for (int i = 0; i < 4; ++i) {
        const int row = wave * 32 + i * 8 + (lane >> 3);
        int m = mtile * 128 + row;
        if (m >= MTOT) m = MTOT - 1;
        const int oh = m / OWD, ow = m - oh * OWD;
        Asrc[i] = Xbf + (((size_t)b * 128 + oh) * 128 + ow) * 128 + kc * 8;
        Bsrc[i] = Bt + ((size_t)b * 128 + row) * 1152 + kc * 8;
    }
    uint16_t* Adst = &lA[(wave * 256 + lane) * 8];
    uint16_t* Bdst = &lB[(wave * 256 + lane) * 8];

    f32x4 acc[4][4];
#pragma unroll
    for (int i = 0; i < 4; ++i)
#pragma unroll
        for (int j = 0; j < 4; ++j)
            acc[i][j] = (f32x4){0.f, 0.f, 0.f, 0.f};

    for (int rs = 0; rs < 9; ++rs) {
        const int r = rs / 3;
        const int s = rs - r * 3;
        const int aoff = (r * 128 + s) * 128;
        const int boff = rs * 128;
#pragma unroll
        for (int half = 0; half < 2; ++half) {
            const int c0 = half * 64;

            __syncthreads();
#pragma unroll
            for (int i = 0; i < 4; ++i) {
                gl_lds16(Asrc[i] + aoff + c0, Adst + i * 512);
                gl_lds16(Bsrc[i] + boff + c0, Bdst + i * 512);
            }
            __syncthreads();

#pragma unroll
            for (int ksub = 0; ksub < 2; ++ksub) {
                bf16x8 af[4], bfr[4];
#pragma unroll
                for (int i = 0; i < 4; ++i) {
                    const int row = wm + i * 16 + l15;
                    const int pc  = (ksub * 4 + quad) ^ (row & 7);
                    af[i] = *(const bf16x8*)&lA[row * 64 + pc * 8];
                }
#pragma unroll
                for (int j = 0; j < 4; ++j) {
                    const int row = wn + j * 16 + l15;
                    const int pc  = (ksub * 4 + quad) ^ (row & 7);
                    bfr[j] = *(const bf16x8*)&lB[row * 64 + pc * 8];
                }
#pragma unroll
                for (int i = 0; i < 4; ++i)
#pragma unroll
                    for (int j = 0; j < 4; ++j)
                        acc[i][j] = __builtin_amdgcn_mfma_f32_16x16x32_bf16(
                            af[i], bfr[j], acc[i][j], 0, 0, 0);
            }
        }
    }

    // epilogue: D row = quad*4+reg, col = lane&15 (verified round 1)
#pragma unroll
    for (int i = 0; i < 4; ++i) {
#pragma unroll
        for (int rr = 0; rr < 4; ++rr) {
            const int mrow = mtile * 128 + wm + i * 16 + quad * 4 + rr;
            if (mrow < MTOT) {
                const int oh2 = mrow / OWD;
                const int ow2 = mrow - oh2 * OWD;
                float* op = Out + (((size_t)b * OWD + oh2) * OWD + ow2) * 128 + wn + l15;
#pragma unroll
                for (int j = 0; j < 4; ++j)
                    op[j * 16] = acc[i][j][rr];
            }
        }
    }
}

// ---------------------------------------------------------------------------
// Fallback (ws too small): round-1 kernel, fp32 X with in-kernel cvt.
// ---------------------------------------------------------------------------
__global__ __launch_bounds__(256) void conv_mfma(const float* __restrict__ X,
                                                 const uint16_t* __restrict__ Bt,
                                                 float* __restrict__ Out) {
    __shared__ __align__(16) uint16_t lA[128 * 64];
    __shared__ __align__(16) uint16_t lB[128 * 64];

    const int mtile = blockIdx.x;
    const int b     = blockIdx.y;
    const int tid   = threadIdx.x;
    const int lane  = tid & 63;
    const int wave  = tid >> 6;
    const int wm    = (wave & 1) << 6;
    const int wn    = (wave >> 1) << 6;
    const int l15   = lane & 15;
    const int quad  = lane >> 4;

    const int srow  = tid >> 1;
    const int shalf = tid & 1;

    int m = mtile * 128 + srow;
    if (m >= MTOT) m = MTOT - 1;
    const int oh = m / OWD;
    const int ow = m - oh * OWD;
    const float*    Xb = X + (((size_t)b * 128 + oh) * 128 + ow) * 128;
    const uint16_t* Bb = Bt + ((size_t)b * 128 + srow) * 1152 + shalf * 32;

    f32x4 acc[4][4];
#pragma unroll
    for (int i = 0; i < 4; ++i)
#pragma unroll
        for (int j = 0; j < 4; ++j)
            acc[i][j] = (f32x4){0.f, 0.f, 0.f, 0.f};

    for (int chunk = 0; chunk < 18; ++chunk) {
        const int rs = chunk >> 1;
        const int c0 = (chunk & 1) << 6;
        const int r  = rs / 3;
        const int s  = rs - r * 3;

        __syncthreads();
        {
            const float4* src = (const float4*)(Xb + (r * 128 + s) * 128 + c0 + shalf * 32);
            float4 v[8];
#pragma unroll
            for (int i = 0; i < 8; ++i) v[i] = src[i];
#pragma unroll
            for (int i = 0; i < 4; ++i) {
                uint4 p;
                p.x = pk2(v[2 * i].x, v[2 * i].y);
                p.y = pk2(v[2 * i].z, v[2 * i].w);
                p.z = pk2(v[2 * i + 1].x, v[2 * i + 1].y);
                p.w = pk2(v[2 * i + 1].z, v[2 * i + 1].w);
                const int ci = (shalf * 4 + i) ^ (srow & 7);
                *(uint4*)&lA[srow * 64 + ci * 8] = p;
            }
        }
        {
            const uint4* bsrc = (const uint4*)(Bb + rs * 128 + c0);
#pragma unroll
            for (int i = 0; i < 4; ++i) {
                const uint4 p = bsrc[i];
                const int ci = (shalf * 4 + i) ^ (srow & 7);
                *(uint4*)&lB[srow * 64 + ci * 8] = p;
            }
        }
        __syncthreads();

#pragma unroll
        for (int ksub = 0; ksub < 2; ++ksub) {
            bf16x8 af[4], bfr[4];
#pragma unroll
            for (int i = 0; i < 4; ++i) {
                const int row = wm + i * 16 + l15;
                const int ci  = (ksub * 4 + quad) ^ (row & 7);
                af[i] = *(const bf16x8*)&lA[row * 64 + ci * 8];
            }
#pragma unroll
            for (int j = 0; j < 4; ++j) {
                const int row = wn + j * 16 + l15;
                const int ci  = (ksub * 4 + quad) ^ (row & 7);
                bfr[j] = *(const bf16x8*)&lB[row * 64 + ci * 8];
            }
#pragma unroll
            for (int i = 0; i < 4; ++i)
#pragma unroll
                for (int j = 0; j < 4; ++j)
                    acc[i][j] = __builtin_amdgcn_mfma_f32_16x16x32_bf16(
                        af[i], bfr[j], acc[i][j], 0, 0, 0);
        }
    }

#pragma unroll
    for (int i = 0; i < 4; ++i) {
#pragma unroll
        for (int rr = 0; rr < 4; ++rr) {
            const int mrow = mtile * 128 + wm + i * 16 + quad * 4 + rr;
            if (mrow < MTOT) {
                const int oh2 = mrow / OWD;
                const int ow2 = mrow - oh2 * OWD;
                float* op = Out + (((size_t)b * OWD + oh2) * OWD + ow2) * 128 + wn + l15;
#pragma unroll
                for (int j = 0; j < 4; ++j)
                    op[j * 16] = acc[i][j][rr];
            }
        }
    }
}

extern "C" void kernel_launch(void* const* d_in, const int* in_sizes, int n_in,
                              void* d_out, int out_size, void* d_ws, size_t ws_size,
                              hipStream_t stream) {
    const float* X   = (const float*)d_in[0];   // [16,128,128,128]
    const float* Kin = (const float*)d_in[1];   // [16,3,3,128,128]
    float*       Out = (float*)d_out;           // [16,126,126,128]
    uint16_t*    Bt  = (uint16_t*)d_ws;         // bf16 [16][128][1152]
    uint16_t*    Xbf = Bt + BT_ELEMS;           // bf16 [16][128][128][128]

    kprep<<<dim3(9, 16), 256, 0, stream>>>(Kin, Bt);
    if (ws_size >= WS_NEEDED) {
        xprep<<<XBF_ELEMS / (256 * 8), 256, 0, stream>>>(X, Xbf);
        conv_mfma_a<<<dim3(125, 16), 256, 0, stream>>>(Xbf, Bt, Out);
    } else {
        conv_mfma<<<dim3(125, 16), 256, 0, stream>>>(X, Bt, Out);
    }
}